// Round 9
// baseline (1803.968 us; speedup 1.0000x reference)
//
#include <hip/hip_runtime.h>
#include <hip/hip_bf16.h>
#include <math.h>

#define B_ 2
#define L_ 2048
#define D_ 1024
#define VOCAB_ 65536
#define TOOLV_ 128
#define NCONV_ 10
#define NATTN_ 6
#define HEADS_ 8
#define HD_ 128
#define EPS_ 1e-5f

typedef short bf16x8 __attribute__((ext_vector_type(8)));
typedef short short4v __attribute__((ext_vector_type(4)));
typedef float f32x4 __attribute__((ext_vector_type(4)));
#define MFMA16(a,b,c) __builtin_amdgcn_mfma_f32_16x16x32_bf16(a, b, c, 0, 0, 0)

__device__ inline short f2bf(float f) {
  __hip_bfloat16 h = __float2bfloat16(f);
  return *reinterpret_cast<short*>(&h);
}

__device__ __forceinline__ void gld16(const void* g, void* l) {
  __builtin_amdgcn_global_load_lds(
      (const __attribute__((address_space(1))) unsigned int*)g,
      (__attribute__((address_space(3))) unsigned int*)l, 16, 0, 0);
}

__device__ __forceinline__ void sync_prefetch() {
  asm volatile("s_waitcnt vmcnt(0)" ::: "memory");
  __builtin_amdgcn_s_barrier();
  __builtin_amdgcn_sched_barrier(0);
}

// ---------------- Julia feats + projection (float4) ----------------
__global__ __launch_bounds__(256) void julia_proj_k(const float* __restrict__ cs,
    const float* __restrict__ pw, const float* __restrict__ esc, float* __restrict__ h) {
  int row = blockIdx.x;                       // b*L + l
  float cr = cs[2*(size_t)row], ci = cs[2*(size_t)row+1];
  float f[16];
  float zr = 0.f, zi = 0.f;
  #pragma unroll
  for (int s = 0; s < 8; ++s) {
    float nzr = zr*zr - zi*zi + cr;
    float nzi = 2.f*zr*zi + ci;
    zr = nzr; zi = nzi;
    f[2*s] = zr; f[2*s+1] = zi;
  }
  float e = esc[0];
  int d = threadIdx.x * 4;
  float4 acc = {0.f, 0.f, 0.f, 0.f};
  #pragma unroll
  for (int i = 0; i < 16; ++i) {
    float4 pv = *(const float4*)(pw + i*D_ + d);
    acc.x += f[i]*pv.x; acc.y += f[i]*pv.y; acc.z += f[i]*pv.z; acc.w += f[i]*pv.w;
  }
  acc.x *= e; acc.y *= e; acc.z *= e; acc.w *= e;
  *(float4*)(h + (size_t)row*D_ + d) = acc;
}

// ---------------- depthwise conv over L (K=5, pad 2), float4, bf16 out ------
__global__ __launch_bounds__(256) void dwconv_k(const float* __restrict__ x,
    const float* __restrict__ w, const float* __restrict__ bias, short* __restrict__ y) {
  int idx = blockIdx.x*256 + threadIdx.x;              // over M * D/4
  int d = (idx & (D_/4 - 1)) * 4;
  int bl = idx >> 8;
  int l = bl & (L_-1);
  size_t bbase = (size_t)(bl >> 11) * L_;              // b*L
  float4 acc = *(const float4*)(bias + d);
  float wr[4][5];
  #pragma unroll
  for (int j = 0; j < 4; ++j)
    #pragma unroll
    for (int k = 0; k < 5; ++k) wr[j][k] = w[(d+j)*5 + k];
  #pragma unroll
  for (int k = 0; k < 5; ++k) {
    int ll = l + k - 2;
    if (ll >= 0 && ll < L_) {
      float4 xv = *(const float4*)(x + (bbase + ll)*D_ + d);
      acc.x += xv.x*wr[0][k]; acc.y += xv.y*wr[1][k];
      acc.z += xv.z*wr[2][k]; acc.w += xv.w*wr[3][k];
    }
  }
  short4v o = { f2bf(acc.x), f2bf(acc.y), f2bf(acc.z), f2bf(acc.w) };
  ((short4v*)y)[idx] = o;
}

// ---------------- conv pw weight: fp32 (N,K) -> bf16 permuted (N,K) ----------
__global__ __launch_bounds__(256) void cvt_perm_k(const float* __restrict__ W,
    short* __restrict__ out) {
  int z = blockIdx.y;
  int i4 = blockIdx.x*256 + threadIdx.x;       // float4 idx within layer
  int e = i4*4;
  int r = e >> 10, k = e & 1023;
  int t = r >> 7, wn = (r >> 6) & 1, j = r & 63;
  int u = t*64 + wn*32 + (j & 31);
  int src = (j < 32) ? u : 1024 + u;
  const float* p = W + ((size_t)z*2048 + src)*1024 + k;
  float4 v = *(const float4*)p;
  short4v s = { f2bf(v.x), f2bf(v.y), f2bf(v.z), f2bf(v.w) };
  *(short4v*)(out + ((size_t)z*2048 + r)*1024 + k) = s;
}

// (K,N) fp32 -> (N,K) bf16 transpose, batched over blockIdx.z layers
__global__ __launch_bounds__(256) void transp_bf16_k(const float* __restrict__ W0,
    short* __restrict__ WT0, int K, int N, size_t srcStride, size_t dstStride) {
  const float* W = W0 + blockIdx.z*srcStride;
  short* WT = WT0 + blockIdx.z*dstStride;
  __shared__ short t[32][33];
  int n0 = blockIdx.x*32, k0 = blockIdx.y*32;
  int tx = threadIdx.x & 31, ty = threadIdx.x >> 5;   // ty 0..7
  #pragma unroll
  for (int i = 0; i < 4; ++i) {
    int k = ty + i*8;
    t[tx][k] = f2bf(W[(size_t)(k0+k)*N + n0 + tx]);
  }
  __syncthreads();
  #pragma unroll
  for (int i = 0; i < 4; ++i) {
    int n = ty + i*8;
    WT[(size_t)(n0+n)*K + k0 + tx] = t[n][tx];
  }
}

// ---------------- bf16 MFMA GEMM: A(M,K)bf16 x Bt(N,K)bf16 -----
// 128xBN tile, BK=32 dbuf + issue-early prefetch, XCD-chunked block swizzle.
// MODE 0: fp32 C.  MODE 3: fused QKV epilogue (BN=128).  MODE 4: fused GLU
// (permuted B, BN=128), writes C (M x 1024) fp32 = a*sigmoid(gate).
template<int MODE, int BN>
__global__ __launch_bounds__(256) void gemm_bf16(const short* __restrict__ A,
    const short* __restrict__ Bt, const float* __restrict__ bias,
    float* __restrict__ C, short* __restrict__ obf,
    short* __restrict__ kbf, short* __restrict__ vtbf,
    float scale, int M, int N, int K) {
  constexpr int NI = BN/32;          // B fragments per wave (4 for 128, 2 for 64)
  __shared__ short As[2][128*32];
  __shared__ short Bs[2][BN*32];
  const int tid  = threadIdx.x;
  const int lane = tid & 63;
  const int wave = tid >> 6;
  const int wm = wave >> 1, wn = wave & 1;
  const int g = lane >> 4, c = lane & 15;

  // XCD-chunked bijective swizzle (gridDim.x = 32 always; nwg % 8 == 0)
  int flat = blockIdx.y * gridDim.x + blockIdx.x;
  int nwg  = gridDim.x * gridDim.y;
  int swz  = (flat & 7) * (nwg >> 3) + (flat >> 3);
  const int m0 = (swz & 31) * 128;
  const int n0 = (swz >> 5) * BN;

  f32x4 acc[4][NI];
  #pragma unroll
  for (int i = 0; i < 4; ++i)
    #pragma unroll
    for (int j = 0; j < NI; ++j) acc[i][j] = (f32x4){0.f,0.f,0.f,0.f};

  const int srow = wave*16 + (lane>>2);
  const int scol = (lane&3)*8;
  const short* aSrc0 = A + (size_t)(m0 + srow)*K + scol;
  const short* aSrc1 = aSrc0 + (size_t)64*K;
  const short* bSrc0 = Bt + (size_t)(n0 + srow)*K + scol;
  const short* bSrc1 = bSrc0 + (size_t)64*K;
  const int woff = wave*512;

  gld16(aSrc0, &As[0][woff]);
  gld16(aSrc1, &As[0][woff + 2048]);
  gld16(bSrc0, &Bs[0][woff]);
  if (BN == 128) gld16(bSrc1, &Bs[0][woff + 2048]);
  sync_prefetch();

  const int nt = K >> 5;
  int cur = 0;
  for (int t = 0; t < nt; ++t) {
    if (t + 1 < nt) {
      int k0 = (t + 1) << 5;
      gld16(aSrc0 + k0, &As[cur^1][woff]);
      gld16(aSrc1 + k0, &As[cur^1][woff + 2048]);
      gld16(bSrc0 + k0, &Bs[cur^1][woff]);
      if (BN == 128) gld16(bSrc1 + k0, &Bs[cur^1][woff + 2048]);
    }
    bf16x8 af[4], bfr[NI];
    #pragma unroll
    for (int mi = 0; mi < 4; ++mi)
      af[mi] = *(const bf16x8*)&As[cur][(wm*64 + mi*16 + c)*32 + g*8];
    #pragma unroll
    for (int ni = 0; ni < NI; ++ni)
      bfr[ni] = *(const bf16x8*)&Bs[cur][(wn*(BN/2) + ni*16 + c)*32 + g*8];
    #pragma unroll
    for (int mi = 0; mi < 4; ++mi)
      #pragma unroll
      for (int ni = 0; ni < NI; ++ni)
        acc[mi][ni] = MFMA16(af[mi], bfr[ni], acc[mi][ni]);
    if (t + 1 < nt) {
      sync_prefetch();
      cur ^= 1;
    }
  }

  if (MODE == 4) {
    // permuted cols: pair (a, gate) sits at (ni, ni+2); output col u in [0,1024)
    #pragma unroll
    for (int mi = 0; mi < 4; ++mi) {
      int row = m0 + wm*64 + mi*16 + g*4;
      #pragma unroll
      for (int ni = 0; ni < 2; ++ni) {
        int u = (n0 >> 7)*64 + wn*32 + ni*16 + c;
        float ba = bias[u], bg = bias[1024 + u];
        #pragma unroll
        for (int r = 0; r < 4; ++r) {
          float a  = acc[mi][ni][r]   + ba;
          float gt = acc[mi][ni+2][r] + bg;
          C[(size_t)(row+r)*1024 + u] = a / (1.f + expf(-gt));
        }
      }
    }
    return;
  }

  #pragma unroll
  for (int mi = 0; mi < 4; ++mi) {
    int row = m0 + wm*64 + mi*16 + g*4;
    #pragma unroll
    for (int ni = 0; ni < NI; ++ni) {
      int col = n0 + wn*(BN/2) + ni*16 + c;
      if (MODE == 0) {
        #pragma unroll
        for (int r = 0; r < 4; ++r)
          C[(size_t)(row+r)*N + col] = acc[mi][ni][r];
      } else {  // MODE 3
        if (col < 1024) {
          #pragma unroll
          for (int r = 0; r < 4; ++r)
            obf[(size_t)(row+r)*1024 + col] = f2bf(acc[mi][ni][r]*scale);
        } else {
          int col2 = col - 1024;
          int hh = col2 >> 8, jj = (col2 >> 7) & 1, d = col2 & 127;
          int bb = row >> 11, l = row & 2047;
          size_t bh = (size_t)bb*8 + hh;
          if (jj == 0) {
            #pragma unroll
            for (int r = 0; r < 4; ++r)
              kbf[(bh*L_ + l + r)*128 + d] = f2bf(acc[mi][ni][r]);
          } else {
            #pragma unroll
            for (int r = 0; r < 4; ++r)
              vtbf[(bh*128 + d)*L_ + l + r] = f2bf(acc[mi][ni][r]);
          }
        }
      }
    }
  }
}

// ---------------- residual + LayerNorm (float4, regs, opt bf16 out) ----------
__global__ __launch_bounds__(256) void resid_ln_k(float* __restrict__ h,
    const float* __restrict__ proj, const float* __restrict__ s, const float* __restrict__ b,
    short* __restrict__ bo) {
  int row = blockIdx.x;
  int tid = threadIdx.x;
  int d = tid*4;
  float* xr = h + (size_t)row*D_;
  const float* pr = proj + (size_t)row*D_;
  __shared__ float red[256];
  float4 xv = *(const float4*)(xr + d);
  float4 pv = *(const float4*)(pr + d);
  float v[4] = { xv.x+pv.x, xv.y+pv.y, xv.z+pv.z, xv.w+pv.w };
  red[tid] = v[0]+v[1]+v[2]+v[3]; __syncthreads();
  for (int st = 128; st > 0; st >>= 1) { if (tid < st) red[tid] += red[tid+st]; __syncthreads(); }
  float mu = red[0] * (1.f/D_); __syncthreads();
  float lv = 0.f;
  #pragma unroll
  for (int j = 0; j < 4; ++j) { float dd = v[j]-mu; lv += dd*dd; }
  red[tid] = lv; __syncthreads();
  for (int st = 128; st > 0; st >>= 1) { if (tid < st) red[tid] += red[tid+st]; __syncthreads(); }
  float var = red[0] * (1.f/D_);
  float r = 1.f/sqrtf(var + EPS_);
  float4 sv = *(const float4*)(s + d);
  float4 bv = *(const float4*)(b + d);
  float4 o;
  o.x = (v[0]-mu)*r*sv.x + bv.x;
  o.y = (v[1]-mu)*r*sv.y + bv.y;
  o.z = (v[2]-mu)*r*sv.z + bv.z;
  o.w = (v[3]-mu)*r*sv.w + bv.w;
  *(float4*)(xr + d) = o;
  if (bo) {
    short4v ob = { f2bf(o.x), f2bf(o.y), f2bf(o.z), f2bf(o.w) };
    *(short4v*)(bo + (size_t)row*D_ + d) = ob;
  }
}

// ---------------- flash attention: bf16 in, swizzled dbuf LDS, prefetch ------
#define PPITCH 72
__global__ __launch_bounds__(256) void attn2_k(const short* __restrict__ qbf,
    const short* __restrict__ kbf, const short* __restrict__ vtbf,
    short* __restrict__ obf) {
  __shared__ short Ks[2][64*128];   // [kv 64][d 128] swizzled 16B blocks
  __shared__ short Vts[2][128*64];  // [d 128][kv 64] swizzled 16B blocks
  __shared__ short Ps[4*16*PPITCH];

  const int tid  = threadIdx.x;
  const int wave = tid >> 6;
  const int lane = tid & 63;
  const int g    = lane >> 4;
  const int c    = lane & 15;

  int flat = blockIdx.x;                        // 512 blocks
  int swz  = (flat & 7)*64 + (flat >> 3);       // chunk 64/XCD = 2 bh
  const int qt = swz & 31;
  const int hh = (swz >> 5) & 7;
  const int b  = swz >> 8;
  const int q0 = qt*64 + wave*16;
  const size_t bh = (size_t)(b*HEADS_ + hh);

  bf16x8 qf[4];
  {
    const short* Qp = qbf + ((size_t)(b*L_ + q0 + c))*D_ + hh*HD_;
    #pragma unroll
    for (int kd = 0; kd < 4; ++kd)
      qf[kd] = *(const bf16x8*)(Qp + kd*32 + g*8);
  }

  f32x4 O[8];
  #pragma unroll
  for (int i = 0; i < 8; ++i) O[i] = (f32x4){0.f,0.f,0.f,0.f};
  float mrun[4] = {-INFINITY,-INFINITY,-INFINITY,-INFINITY};
  float lrun[4] = {0.f,0.f,0.f,0.f};
  short* Pw = Ps + wave*16*PPITCH;

  const short* kBase = kbf + bh*L_*128;
  const short* vBase = vtbf + bh*128*L_;

  auto stage = [&](int t, int buf) {
    #pragma unroll
    for (int rd = 0; rd < 4; ++rd) {
      int slot = rd*256 + tid;
      int kr = slot >> 4, kj = slot & 15;
      int vr = slot >> 3, vj = slot & 7;
      gld16(kBase + ((size_t)(t*64 + kr))*128 + ((kj ^ (kr & 15)) * 8),
            (char*)&Ks[buf][0] + (rd*256 + wave*64)*16);
      gld16(vBase + (size_t)vr*L_ + t*64 + ((vj ^ (vr & 7)) * 8),
            (char*)&Vts[buf][0] + (rd*256 + wave*64)*16);
    }
  };

  stage(0, 0);
  sync_prefetch();
  int cur = 0;
  const int NT = L_/64;

  for (int t = 0; t < NT; ++t) {
    if (t + 1 < NT) stage(t + 1, cur^1);

    f32x4 s[4];
    #pragma unroll
    for (int nc = 0; nc < 4; ++nc) {
      s[nc] = (f32x4){0.f,0.f,0.f,0.f};
      int R = nc*16 + c;
      #pragma unroll
      for (int kd = 0; kd < 4; ++kd) {
        bf16x8 kf = *(const bf16x8*)&Ks[cur][R*128 + (((kd*4 + g) ^ (R & 15)) * 8)];
        s[nc] = MFMA16(qf[kd], kf, s[nc]);
      }
    }

    float tm[4], rsum[4], alpha[4];
    #pragma unroll
    for (int r = 0; r < 4; ++r)
      tm[r] = fmaxf(fmaxf(s[0][r], s[1][r]), fmaxf(s[2][r], s[3][r]));
    #pragma unroll
    for (int r = 0; r < 4; ++r) {
      #pragma unroll
      for (int mask = 1; mask <= 8; mask <<= 1)
        tm[r] = fmaxf(tm[r], __shfl_xor(tm[r], mask));
      float mnew = fmaxf(mrun[r], tm[r]);
      alpha[r] = expf(mrun[r] - mnew);
      mrun[r] = mnew;
      rsum[r] = 0.f;
    }
    #pragma unroll
    for (int nc = 0; nc < 4; ++nc)
      #pragma unroll
      for (int r = 0; r < 4; ++r) {
        float p = expf(s[nc][r] - mrun[r]);
        s[nc][r] = p;
        rsum[r] += p;
      }
    #pragma unroll
    for (int r = 0; r < 4; ++r) {
      #pragma unroll
      for (int mask = 1; mask <= 8; mask <<= 1)
        rsum[r] += __shfl_xor(rsum[r], mask);
      lrun[r] = lrun[r]*alpha[r] + rsum[r];
    }
    #pragma unroll
    for (int nc = 0; nc < 8; ++nc)
      #pragma unroll
      for (int r = 0; r < 4; ++r) O[nc][r] *= alpha[r];

    #pragma unroll
    for (int nc = 0; nc < 4; ++nc)
      #pragma unroll
      for (int r = 0; r < 4; ++r)
        Pw[(g*4+r)*PPITCH + nc*16 + c] = f2bf(s[nc][r]);
    asm volatile("s_waitcnt lgkmcnt(0)" ::: "memory");
    bf16x8 pa0 = *(const bf16x8*)&Pw[c*PPITCH + g*8];
    bf16x8 pa1 = *(const bf16x8*)&Pw[c*PPITCH + 32 + g*8];

    #pragma unroll
    for (int ks = 0; ks < 2; ++ks) {
      #pragma unroll
      for (int nc = 0; nc < 8; ++nc) {
        int R = nc*16 + c;
        bf16x8 vf = *(const bf16x8*)&Vts[cur][R*64 + (((ks*4 + g) ^ (R & 7)) * 8)];
        O[nc] = MFMA16(ks ? pa1 : pa0, vf, O[nc]);
      }
    }

    if (t + 1 < NT) {
      sync_prefetch();
      cur ^= 1;
    }
  }

  short* ob = obf + ((size_t)(b*L_ + q0))*D_ + hh*HD_;
  #pragma unroll
  for (int r = 0; r < 4; ++r) {
    float inv = 1.f / lrun[r];
    #pragma unroll
    for (int nc = 0; nc < 8; ++nc)
      ob[(size_t)(g*4+r)*D_ + nc*16 + c] = f2bf(O[nc][r] * inv);
  }
}

// ---------------- heads ----------------
// lm partials: part[ks][j][VOCAB], ks=0..7 k-chunks (128 each), j=batch
__global__ __launch_bounds__(256) void lm_head_part_k(const float* __restrict__ h,
    const float* __restrict__ lm_w, float* __restrict__ part) {
  int tid = threadIdx.x;
  int n = (blockIdx.x*256 + tid)*4;
  int ks = blockIdx.y;
  __shared__ float last0[128], last1[128];
  const float* h0 = h + ((size_t)0*L_ + (L_-1))*D_ + ks*128;
  const float* h1 = h + ((size_t)1*L_ + (L_-1))*D_ + ks*128;
  if (tid < 128) { last0[tid] = h0[tid]; last1[tid] = h1[tid]; }
  __syncthreads();
  float4 a0 = {0.f,0.f,0.f,0.f}, a1 = {0.f,0.f,0.f,0.f};
  const float* wp = lm_w + (size_t)(ks*128)*VOCAB_ + n;
  for (int kk = 0; kk < 128; ++kk) {
    float4 wv = *(const float4*)(wp + (size_t)kk*VOCAB_);
    float c0 = last0[kk], c1 = last1[kk];
    a0.x += c0*wv.x; a0.y += c0*wv.y; a0.z += c0*wv.z; a0.w += c0*wv.w;
    a1.x += c1*wv.x; a1.y += c1*wv.y; a1.z += c1*wv.z; a1.w += c1*wv.w;
  }
  *(float4*)(part + ((size_t)ks*2 + 0)*VOCAB_ + n) = a0;
  *(float4*)(part + ((size_t)ks*2 + 1)*VOCAB_ + n) = a1;
}

__global__ __launch_bounds__(256) void lm_head_red_k(const float* __restrict__ part,
    float* __restrict__ out) {
  int i = blockIdx.x*256 + threadIdx.x;        // over 2*VOCAB/4 float4s
  int j = (i*4) / VOCAB_;
  int n = (i*4) & (VOCAB_-1);
  float4 acc = {0.f,0.f,0.f,0.f};
  #pragma unroll
  for (int ks = 0; ks < 8; ++ks) {
    float4 v = *(const float4*)(part + ((size_t)ks*2 + j)*VOCAB_ + n);
    acc.x += v.x; acc.y += v.y; acc.z += v.z; acc.w += v.w;
  }
  *(float4*)(out + (size_t)j*VOCAB_ + n) = acc;
}

__global__ __launch_bounds__(128) void tool_head_k(const float* __restrict__ h,
    const float* __restrict__ tw, const float* __restrict__ tb, float* __restrict__ out) {
  int b = blockIdx.x;
  int tid = threadIdx.x;
  __shared__ float last[D_];
  const float* hr = h + ((size_t)b*L_ + (L_-1))*D_;
  for (int d = tid; d < D_; d += 128) last[d] = hr[d];
  __syncthreads();
  float acc = tb[tid];
  for (int k = 0; k < D_; ++k) acc += last[k]*tw[(size_t)k*TOOLV_ + tid];
  out[(size_t)2*VOCAB_ + (size_t)b*TOOLV_ + tid] = acc;
}

extern "C" void kernel_launch(void* const* d_in, const int* in_sizes, int n_in,
                              void* d_out, int out_size, void* d_ws, size_t ws_size,
                              hipStream_t stream) {
  const float* cs        = (const float*)d_in[1];
  const float* proj_w    = (const float*)d_in[2];
  const float* emb_scale = (const float*)d_in[3];
  const float* conv_dw_w = (const float*)d_in[4];
  const float* conv_dw_b = (const float*)d_in[5];
  const float* conv_pw_w = (const float*)d_in[6];
  const float* conv_pw_b = (const float*)d_in[7];
  const float* conv_ln_s = (const float*)d_in[8];
  const float* conv_ln_b = (const float*)d_in[9];
  const float* attn_q_w  = (const float*)d_in[10];
  const float* attn_kv_w = (const float*)d_in[11];
  const float* attn_out_w= (const float*)d_in[12];
  const float* attn_ln_s = (const float*)d_in[13];
  const float* attn_ln_b = (const float*)d_in[14];
  const float* lm_w      = (const float*)d_in[15];
  const float* tool_w    = (const float*)d_in[16];
  const float* tool_b    = (const float*)d_in[17];

  const int M = B_*L_;                              // 4096
  float* h    = (float*)d_ws;                       // M*D fp32
  float* buf2 = h    + (size_t)M*D_;                // M*2D fp32 (lower: proj/glu; upper: qbf)
  short* kbf  = (short*)(buf2 + (size_t)M*2*D_);    // B*H*L*128 bf16
  short* vtbf = kbf + (size_t)B_*HEADS_*L_*128;     // B*H*128*L bf16
  short* abf  = (short*)(vtbf + (size_t)B_*HEADS_*128*L_);  // M*D bf16
  short* wconv= abf + (size_t)M*D_;                 // 10 * 2D*D bf16 (permuted)
  short* wqkv = wconv + (size_t)NCONV_*2*D_*D_;     // 6 * 3D*D bf16
  short* wout = wqkv + (size_t)NATTN_*3*D_*D_;      // 6 * D*D bf16
  float* lmpart = (float*)(wout + (size_t)NATTN_*D_*D_);  // 8*2*VOCAB fp32
  short* qbf  = (short*)(buf2 + (size_t)M*D_);      // M*D bf16 (upper half of buf2)

  const float scale = 0.088388347648318447f;        // 128^-0.5

  // ---- batched weight prep (4 launches) ----
  {
    cvt_perm_k<<<dim3((2*D_*D_/4)/256, NCONV_), 256, 0, stream>>>(conv_pw_w, wconv);
    transp_bf16_k<<<dim3(D_/32, D_/32, NATTN_), 256, 0, stream>>>(
        attn_q_w, wqkv, D_, D_, (size_t)D_*D_, (size_t)3*D_*D_);
    transp_bf16_k<<<dim3((2*D_)/32, D_/32, NATTN_), 256, 0, stream>>>(
        attn_kv_w, wqkv + (size_t)D_*D_, D_, 2*D_, (size_t)D_*2*D_, (size_t)3*D_*D_);
    transp_bf16_k<<<dim3(D_/32, D_/32, NATTN_), 256, 0, stream>>>(
        attn_out_w, wout, D_, D_, (size_t)D_*D_, (size_t)D_*D_);
  }

  julia_proj_k<<<M, 256, 0, stream>>>(cs, proj_w, emb_scale, h);

  for (int i = 0; i < NCONV_; ++i) {
    dwconv_k<<<(M*D_/4)/256, 256, 0, stream>>>(h, conv_dw_w + (size_t)i*D_*5,
                                               conv_dw_b + (size_t)i*D_, abf);
    gemm_bf16<4, 128><<<dim3(M/128, (2*D_)/128), 256, 0, stream>>>(
        abf, wconv + (size_t)i*2*D_*D_, conv_pw_b + (size_t)i*2*D_,
        buf2, nullptr, nullptr, nullptr, 1.f, M, 2*D_, D_);
    resid_ln_k<<<M, 256, 0, stream>>>(h, buf2, conv_ln_s + (size_t)i*D_,
                                      conv_ln_b + (size_t)i*D_,
                                      (i == NCONV_-1) ? abf : (short*)nullptr);
  }

  for (int i = 0; i < NATTN_; ++i) {
    // abf holds bf16(h) from previous LN
    gemm_bf16<3, 128><<<dim3(M/128, (3*D_)/128), 256, 0, stream>>>(
        abf, wqkv + (size_t)i*3*D_*D_, nullptr, nullptr, qbf, kbf, vtbf,
        scale, M, 3*D_, D_);
    attn2_k<<<(L_/64)*HEADS_*B_, 256, 0, stream>>>(qbf, kbf, vtbf, abf);
    gemm_bf16<0, 64><<<dim3(M/128, D_/64), 256, 0, stream>>>(
        abf, wout + (size_t)i*D_*D_, nullptr, buf2, nullptr, nullptr, nullptr,
        1.f, M, D_, D_);
    resid_ln_k<<<M, 256, 0, stream>>>(h, buf2, attn_ln_s + (size_t)i*D_,
                                      attn_ln_b + (size_t)i*D_,
                                      (i < NATTN_-1) ? abf : (short*)nullptr);
  }

  lm_head_part_k<<<dim3(VOCAB_/1024, 8), 256, 0, stream>>>(h, lm_w, lmpart);
  lm_head_red_k<<<(2*VOCAB_/4)/256, 256, 0, stream>>>(lmpart, (float*)d_out);
  tool_head_k<<<B_, 128, 0, stream>>>(h, tool_w, tool_b, (float*)d_out);
}

// Round 10
// 1691.585 us; speedup vs baseline: 1.0664x; 1.0664x over previous
//
#include <hip/hip_runtime.h>
#include <hip/hip_bf16.h>
#include <math.h>

#define B_ 2
#define L_ 2048
#define D_ 1024
#define VOCAB_ 65536
#define TOOLV_ 128
#define NCONV_ 10
#define NATTN_ 6
#define HEADS_ 8
#define HD_ 128
#define EPS_ 1e-5f

typedef short bf16x8 __attribute__((ext_vector_type(8)));
typedef short short4v __attribute__((ext_vector_type(4)));
typedef float f32x4 __attribute__((ext_vector_type(4)));
#define MFMA16(a,b,c) __builtin_amdgcn_mfma_f32_16x16x32_bf16(a, b, c, 0, 0, 0)

__device__ inline short f2bf(float f) {
  __hip_bfloat16 h = __float2bfloat16(f);
  return *reinterpret_cast<short*>(&h);
}

__device__ __forceinline__ void gld16(const void* g, void* l) {
  __builtin_amdgcn_global_load_lds(
      (const __attribute__((address_space(1))) unsigned int*)g,
      (__attribute__((address_space(3))) unsigned int*)l, 16, 0, 0);
}

__device__ __forceinline__ void sync_prefetch() {
  asm volatile("s_waitcnt vmcnt(0)" ::: "memory");
  __builtin_amdgcn_s_barrier();
  __builtin_amdgcn_sched_barrier(0);
}

// ---------------- Julia feats + projection (float4) ----------------
__global__ __launch_bounds__(256) void julia_proj_k(const float* __restrict__ cs,
    const float* __restrict__ pw, const float* __restrict__ esc, float* __restrict__ h) {
  int row = blockIdx.x;                       // b*L + l
  float cr = cs[2*(size_t)row], ci = cs[2*(size_t)row+1];
  float f[16];
  float zr = 0.f, zi = 0.f;
  #pragma unroll
  for (int s = 0; s < 8; ++s) {
    float nzr = zr*zr - zi*zi + cr;
    float nzi = 2.f*zr*zi + ci;
    zr = nzr; zi = nzi;
    f[2*s] = zr; f[2*s+1] = zi;
  }
  float e = esc[0];
  int d = threadIdx.x * 4;
  float4 acc = {0.f, 0.f, 0.f, 0.f};
  #pragma unroll
  for (int i = 0; i < 16; ++i) {
    float4 pv = *(const float4*)(pw + i*D_ + d);
    acc.x += f[i]*pv.x; acc.y += f[i]*pv.y; acc.z += f[i]*pv.z; acc.w += f[i]*pv.w;
  }
  acc.x *= e; acc.y *= e; acc.z *= e; acc.w *= e;
  *(float4*)(h + (size_t)row*D_ + d) = acc;
}

// ---------------- depthwise conv over L (K=5, pad 2), float4, bf16 out ------
__global__ __launch_bounds__(256) void dwconv_k(const float* __restrict__ x,
    const float* __restrict__ w, const float* __restrict__ bias, short* __restrict__ y) {
  int idx = blockIdx.x*256 + threadIdx.x;              // over M * D/4
  int d = (idx & (D_/4 - 1)) * 4;
  int bl = idx >> 8;
  int l = bl & (L_-1);
  size_t bbase = (size_t)(bl >> 11) * L_;              // b*L
  float4 acc = *(const float4*)(bias + d);
  float wr[4][5];
  #pragma unroll
  for (int j = 0; j < 4; ++j)
    #pragma unroll
    for (int k = 0; k < 5; ++k) wr[j][k] = w[(d+j)*5 + k];
  #pragma unroll
  for (int k = 0; k < 5; ++k) {
    int ll = l + k - 2;
    if (ll >= 0 && ll < L_) {
      float4 xv = *(const float4*)(x + (bbase + ll)*D_ + d);
      acc.x += xv.x*wr[0][k]; acc.y += xv.y*wr[1][k];
      acc.z += xv.z*wr[2][k]; acc.w += xv.w*wr[3][k];
    }
  }
  short4v o = { f2bf(acc.x), f2bf(acc.y), f2bf(acc.z), f2bf(acc.w) };
  ((short4v*)y)[idx] = o;
}

// ---------------- fused residual-LN (layer i) + dwconv (layer i+1) ----------
// Block owns 8 rows; LDS window = 12 rows (2 halo each side), fp32 LN'd values.
// hIn: residual stream (pre-LN), glu: GLU output. Writes hOut = LN'd rows,
// abf = bf16(dwconv(LN'd)) for the next pointwise GEMM.
__global__ __launch_bounds__(256) void ln_dwconv_k(const float* __restrict__ hIn,
    const float* __restrict__ glu, const float* __restrict__ lns,
    const float* __restrict__ lnb, const float* __restrict__ dww,
    const float* __restrict__ dwb, float* __restrict__ hOut,
    short* __restrict__ abf) {
  __shared__ float lds[12][1028];
  const int tid = threadIdx.x;
  const int wv = tid >> 6, ln = tid & 63;
  const int r0 = blockIdx.x * 8;
  const int bb = r0 >> 11;

  float4 sv[4], bv[4];
  #pragma unroll
  for (int q = 0; q < 4; ++q) {
    int d = ln*4 + q*256;
    sv[q] = *(const float4*)(lns + d);
    bv[q] = *(const float4*)(lnb + d);
  }

  #pragma unroll
  for (int i = 0; i < 3; ++i) {
    int lr = wv*3 + i;                       // LDS row 0..11
    int gl = r0 - 2 + lr;
    bool valid = (gl >= (bb << 11)) && (gl < ((bb + 1) << 11));
    if (valid) {
      float4 v4[4];
      float ssum = 0.f;
      #pragma unroll
      for (int q = 0; q < 4; ++q) {
        int d = ln*4 + q*256;
        float4 xv = *(const float4*)(hIn + (size_t)gl*D_ + d);
        float4 pv = *(const float4*)(glu + (size_t)gl*D_ + d);
        v4[q].x = xv.x+pv.x; v4[q].y = xv.y+pv.y;
        v4[q].z = xv.z+pv.z; v4[q].w = xv.w+pv.w;
        ssum += v4[q].x + v4[q].y + v4[q].z + v4[q].w;
      }
      #pragma unroll
      for (int mask = 1; mask < 64; mask <<= 1) ssum += __shfl_xor(ssum, mask);
      float mu = ssum * (1.f/D_);
      float vs = 0.f;
      #pragma unroll
      for (int q = 0; q < 4; ++q) {
        float dx = v4[q].x-mu, dy = v4[q].y-mu, dz = v4[q].z-mu, dw = v4[q].w-mu;
        vs += dx*dx + dy*dy + dz*dz + dw*dw;
      }
      #pragma unroll
      for (int mask = 1; mask < 64; mask <<= 1) vs += __shfl_xor(vs, mask);
      float rr = 1.f/sqrtf(vs*(1.f/D_) + EPS_);
      #pragma unroll
      for (int q = 0; q < 4; ++q) {
        int d = ln*4 + q*256;
        float4 o4;
        o4.x = (v4[q].x-mu)*rr*sv[q].x + bv[q].x;
        o4.y = (v4[q].y-mu)*rr*sv[q].y + bv[q].y;
        o4.z = (v4[q].z-mu)*rr*sv[q].z + bv[q].z;
        o4.w = (v4[q].w-mu)*rr*sv[q].w + bv[q].w;
        *(float4*)&lds[lr][d] = o4;
        if (lr >= 2 && lr < 10)
          *(float4*)(hOut + (size_t)gl*D_ + d) = o4;
      }
    } else {
      float4 z = {0.f,0.f,0.f,0.f};
      #pragma unroll
      for (int q = 0; q < 4; ++q)
        *(float4*)&lds[lr][ln*4 + q*256] = z;
    }
  }
  __syncthreads();

  // dwconv: 8 rows x 1024, zero-padded taps come from zeroed LDS rows.
  int o = tid >> 5;                  // 0..7 (output row within block)
  int cb = (tid & 31) * 4;
  int grow = r0 + o;
  #pragma unroll
  for (int p = 0; p < 8; ++p) {
    int d = cb + p*128;
    float wf[20];
    #pragma unroll
    for (int j = 0; j < 5; ++j)
      *(float4*)&wf[j*4] = *(const float4*)(dww + d*5 + j*4);
    float4 acc = *(const float4*)(dwb + d);
    #pragma unroll
    for (int k = 0; k < 5; ++k) {
      float4 lv = *(const float4*)&lds[o + k][d];
      acc.x += lv.x * wf[k];
      acc.y += lv.y * wf[5 + k];
      acc.z += lv.z * wf[10 + k];
      acc.w += lv.w * wf[15 + k];
    }
    short4v ov = { f2bf(acc.x), f2bf(acc.y), f2bf(acc.z), f2bf(acc.w) };
    *(short4v*)(abf + (size_t)grow*D_ + d) = ov;
  }
}

// ---------------- conv pw weight: fp32 (N,K) -> bf16 permuted (N,K) ----------
__global__ __launch_bounds__(256) void cvt_perm_k(const float* __restrict__ W,
    short* __restrict__ out) {
  int z = blockIdx.y;
  int i4 = blockIdx.x*256 + threadIdx.x;       // float4 idx within layer
  int e = i4*4;
  int r = e >> 10, k = e & 1023;
  int t = r >> 7, wn = (r >> 6) & 1, j = r & 63;
  int u = t*64 + wn*32 + (j & 31);
  int src = (j < 32) ? u : 1024 + u;
  const float* p = W + ((size_t)z*2048 + src)*1024 + k;
  float4 v = *(const float4*)p;
  short4v s = { f2bf(v.x), f2bf(v.y), f2bf(v.z), f2bf(v.w) };
  *(short4v*)(out + ((size_t)z*2048 + r)*1024 + k) = s;
}

// (K,N) fp32 -> (N,K) bf16 transpose, batched over blockIdx.z layers
__global__ __launch_bounds__(256) void transp_bf16_k(const float* __restrict__ W0,
    short* __restrict__ WT0, int K, int N, size_t srcStride, size_t dstStride) {
  const float* W = W0 + blockIdx.z*srcStride;
  short* WT = WT0 + blockIdx.z*dstStride;
  __shared__ short t[32][33];
  int n0 = blockIdx.x*32, k0 = blockIdx.y*32;
  int tx = threadIdx.x & 31, ty = threadIdx.x >> 5;   // ty 0..7
  #pragma unroll
  for (int i = 0; i < 4; ++i) {
    int k = ty + i*8;
    t[tx][k] = f2bf(W[(size_t)(k0+k)*N + n0 + tx]);
  }
  __syncthreads();
  #pragma unroll
  for (int i = 0; i < 4; ++i) {
    int n = ty + i*8;
    WT[(size_t)(n0+n)*K + k0 + tx] = t[n][tx];
  }
}

// q (z<6) and out (z>=6) transposes merged: both 1024x1024.
__global__ __launch_bounds__(256) void transp_qo_k(const float* __restrict__ Wq,
    const float* __restrict__ Wo, short* __restrict__ WTq, short* __restrict__ WTo) {
  int z = blockIdx.z;
  const float* W;
  short* WT;
  if (z < NATTN_) { W = Wq + (size_t)z*D_*D_; WT = WTq + (size_t)z*3*D_*D_; }
  else { W = Wo + (size_t)(z-NATTN_)*D_*D_; WT = WTo + (size_t)(z-NATTN_)*D_*D_; }
  __shared__ short t[32][33];
  int n0 = blockIdx.x*32, k0 = blockIdx.y*32;
  int tx = threadIdx.x & 31, ty = threadIdx.x >> 5;
  #pragma unroll
  for (int i = 0; i < 4; ++i) {
    int k = ty + i*8;
    t[tx][k] = f2bf(W[(size_t)(k0+k)*D_ + n0 + tx]);
  }
  __syncthreads();
  #pragma unroll
  for (int i = 0; i < 4; ++i) {
    int n = ty + i*8;
    WT[(size_t)(n0+n)*D_ + k0 + tx] = t[n][tx];
  }
}

// ---------------- bf16 MFMA GEMM: A(M,K)bf16 x Bt(N,K)bf16 -----
// 128xBN tile, BK=32 dbuf + issue-early prefetch, XCD-chunked block swizzle.
// MODE 0: fp32 C.  MODE 3: fused QKV epilogue (BN=128).  MODE 4: fused GLU
// (permuted B, BN=128), writes C (M x 1024) fp32 = a*sigmoid(gate).
template<int MODE, int BN>
__global__ __launch_bounds__(256) void gemm_bf16(const short* __restrict__ A,
    const short* __restrict__ Bt, const float* __restrict__ bias,
    float* __restrict__ C, short* __restrict__ obf,
    short* __restrict__ kbf, short* __restrict__ vtbf,
    float scale, int M, int N, int K) {
  constexpr int NI = BN/32;          // B fragments per wave (4 for 128, 2 for 64)
  __shared__ short As[2][128*32];
  __shared__ short Bs[2][BN*32];
  const int tid  = threadIdx.x;
  const int lane = tid & 63;
  const int wave = tid >> 6;
  const int wm = wave >> 1, wn = wave & 1;
  const int g = lane >> 4, c = lane & 15;

  // XCD-chunked bijective swizzle (gridDim.x = 32 always; nwg % 8 == 0)
  int flat = blockIdx.y * gridDim.x + blockIdx.x;
  int nwg  = gridDim.x * gridDim.y;
  int swz  = (flat & 7) * (nwg >> 3) + (flat >> 3);
  const int m0 = (swz & 31) * 128;
  const int n0 = (swz >> 5) * BN;

  f32x4 acc[4][NI];
  #pragma unroll
  for (int i = 0; i < 4; ++i)
    #pragma unroll
    for (int j = 0; j < NI; ++j) acc[i][j] = (f32x4){0.f,0.f,0.f,0.f};

  const int srow = wave*16 + (lane>>2);
  const int scol = (lane&3)*8;
  const short* aSrc0 = A + (size_t)(m0 + srow)*K + scol;
  const short* aSrc1 = aSrc0 + (size_t)64*K;
  const short* bSrc0 = Bt + (size_t)(n0 + srow)*K + scol;
  const short* bSrc1 = bSrc0 + (size_t)64*K;
  const int woff = wave*512;

  gld16(aSrc0, &As[0][woff]);
  gld16(aSrc1, &As[0][woff + 2048]);
  gld16(bSrc0, &Bs[0][woff]);
  if (BN == 128) gld16(bSrc1, &Bs[0][woff + 2048]);
  sync_prefetch();

  const int nt = K >> 5;
  int cur = 0;
  for (int t = 0; t < nt; ++t) {
    if (t + 1 < nt) {
      int k0 = (t + 1) << 5;
      gld16(aSrc0 + k0, &As[cur^1][woff]);
      gld16(aSrc1 + k0, &As[cur^1][woff + 2048]);
      gld16(bSrc0 + k0, &Bs[cur^1][woff]);
      if (BN == 128) gld16(bSrc1 + k0, &Bs[cur^1][woff + 2048]);
    }
    bf16x8 af[4], bfr[NI];
    #pragma unroll
    for (int mi = 0; mi < 4; ++mi)
      af[mi] = *(const bf16x8*)&As[cur][(wm*64 + mi*16 + c)*32 + g*8];
    #pragma unroll
    for (int ni = 0; ni < NI; ++ni)
      bfr[ni] = *(const bf16x8*)&Bs[cur][(wn*(BN/2) + ni*16 + c)*32 + g*8];
    #pragma unroll
    for (int mi = 0; mi < 4; ++mi)
      #pragma unroll
      for (int ni = 0; ni < NI; ++ni)
        acc[mi][ni] = MFMA16(af[mi], bfr[ni], acc[mi][ni]);
    if (t + 1 < nt) {
      sync_prefetch();
      cur ^= 1;
    }
  }

  if (MODE == 4) {
    // permuted cols: pair (a, gate) sits at (ni, ni+2); output col u in [0,1024)
    #pragma unroll
    for (int mi = 0; mi < 4; ++mi) {
      int row = m0 + wm*64 + mi*16 + g*4;
      #pragma unroll
      for (int ni = 0; ni < 2; ++ni) {
        int u = (n0 >> 7)*64 + wn*32 + ni*16 + c;
        float ba = bias[u], bg = bias[1024 + u];
        #pragma unroll
        for (int r = 0; r < 4; ++r) {
          float a  = acc[mi][ni][r]   + ba;
          float gt = acc[mi][ni+2][r] + bg;
          C[(size_t)(row+r)*1024 + u] = a / (1.f + expf(-gt));
        }
      }
    }
    return;
  }

  #pragma unroll
  for (int mi = 0; mi < 4; ++mi) {
    int row = m0 + wm*64 + mi*16 + g*4;
    #pragma unroll
    for (int ni = 0; ni < NI; ++ni) {
      int col = n0 + wn*(BN/2) + ni*16 + c;
      if (MODE == 0) {
        #pragma unroll
        for (int r = 0; r < 4; ++r)
          C[(size_t)(row+r)*N + col] = acc[mi][ni][r];
      } else {  // MODE 3
        if (col < 1024) {
          #pragma unroll
          for (int r = 0; r < 4; ++r)
            obf[(size_t)(row+r)*1024 + col] = f2bf(acc[mi][ni][r]*scale);
        } else {
          int col2 = col - 1024;
          int hh = col2 >> 8, jj = (col2 >> 7) & 1, d = col2 & 127;
          int bb = row >> 11, l = row & 2047;
          size_t bh = (size_t)bb*8 + hh;
          if (jj == 0) {
            #pragma unroll
            for (int r = 0; r < 4; ++r)
              kbf[(bh*L_ + l + r)*128 + d] = f2bf(acc[mi][ni][r]);
          } else {
            #pragma unroll
            for (int r = 0; r < 4; ++r)
              vtbf[(bh*128 + d)*L_ + l + r] = f2bf(acc[mi][ni][r]);
          }
        }
      }
    }
  }
}

// ---------------- residual + LayerNorm (float4, regs, opt bf16 out) ----------
__global__ __launch_bounds__(256) void resid_ln_k(float* __restrict__ h,
    const float* __restrict__ proj, const float* __restrict__ s, const float* __restrict__ b,
    short* __restrict__ bo) {
  int row = blockIdx.x;
  int tid = threadIdx.x;
  int d = tid*4;
  float* xr = h + (size_t)row*D_;
  const float* pr = proj + (size_t)row*D_;
  __shared__ float red[256];
  float4 xv = *(const float4*)(xr + d);
  float4 pv = *(const float4*)(pr + d);
  float v[4] = { xv.x+pv.x, xv.y+pv.y, xv.z+pv.z, xv.w+pv.w };
  red[tid] = v[0]+v[1]+v[2]+v[3]; __syncthreads();
  for (int st = 128; st > 0; st >>= 1) { if (tid < st) red[tid] += red[tid+st]; __syncthreads(); }
  float mu = red[0] * (1.f/D_); __syncthreads();
  float lv = 0.f;
  #pragma unroll
  for (int j = 0; j < 4; ++j) { float dd = v[j]-mu; lv += dd*dd; }
  red[tid] = lv; __syncthreads();
  for (int st = 128; st > 0; st >>= 1) { if (tid < st) red[tid] += red[tid+st]; __syncthreads(); }
  float var = red[0] * (1.f/D_);
  float r = 1.f/sqrtf(var + EPS_);
  float4 sv = *(const float4*)(s + d);
  float4 bv = *(const float4*)(b + d);
  float4 o;
  o.x = (v[0]-mu)*r*sv.x + bv.x;
  o.y = (v[1]-mu)*r*sv.y + bv.y;
  o.z = (v[2]-mu)*r*sv.z + bv.z;
  o.w = (v[3]-mu)*r*sv.w + bv.w;
  *(float4*)(xr + d) = o;
  if (bo) {
    short4v ob = { f2bf(o.x), f2bf(o.y), f2bf(o.z), f2bf(o.w) };
    *(short4v*)(bo + (size_t)row*D_ + d) = ob;
  }
}

// ---------------- flash attention: bf16 in, swizzled dbuf LDS, prefetch ------
#define PPITCH 72
__global__ __launch_bounds__(256) void attn2_k(const short* __restrict__ qbf,
    const short* __restrict__ kbf, const short* __restrict__ vtbf,
    short* __restrict__ obf) {
  __shared__ short Ks[2][64*128];   // [kv 64][d 128] swizzled 16B blocks
  __shared__ short Vts[2][128*64];  // [d 128][kv 64] swizzled 16B blocks
  __shared__ short Ps[4*16*PPITCH];

  const int tid  = threadIdx.x;
  const int wave = tid >> 6;
  const int lane = tid & 63;
  const int g    = lane >> 4;
  const int c    = lane & 15;

  int flat = blockIdx.x;                        // 512 blocks
  int swz  = (flat & 7)*64 + (flat >> 3);       // chunk 64/XCD = 2 bh
  const int qt = swz & 31;
  const int hh = (swz >> 5) & 7;
  const int b  = swz >> 8;
  const int q0 = qt*64 + wave*16;
  const size_t bh = (size_t)(b*HEADS_ + hh);

  bf16x8 qf[4];
  {
    const short* Qp = qbf + ((size_t)(b*L_ + q0 + c))*D_ + hh*HD_;
    #pragma unroll
    for (int kd = 0; kd < 4; ++kd)
      qf[kd] = *(const bf16x8*)(Qp + kd*32 + g*8);
  }

  f32x4 O[8];
  #pragma unroll
  for (int i = 0; i < 8; ++i) O[i] = (f32x4){0.f,0.f,0.f,0.f};
  float mrun[4] = {-INFINITY,-INFINITY,-INFINITY,-INFINITY};
  float lrun[4] = {0.f,0.f,0.f,0.f};
  short* Pw = Ps + wave*16*PPITCH;

  const short* kBase = kbf + bh*L_*128;
  const short* vBase = vtbf + bh*128*L_;

  auto stage = [&](int t, int buf) {
    #pragma unroll
    for (int rd = 0; rd < 4; ++rd) {
      int slot = rd*256 + tid;
      int kr = slot >> 4, kj = slot & 15;
      int vr = slot >> 3, vj = slot & 7;
      gld16(kBase + ((size_t)(t*64 + kr))*128 + ((kj ^ (kr & 15)) * 8),
            (char*)&Ks[buf][0] + (rd*256 + wave*64)*16);
      gld16(vBase + (size_t)vr*L_ + t*64 + ((vj ^ (vr & 7)) * 8),
            (char*)&Vts[buf][0] + (rd*256 + wave*64)*16);
    }
  };

  stage(0, 0);
  sync_prefetch();
  int cur = 0;
  const int NT = L_/64;

  for (int t = 0; t < NT; ++t) {
    if (t + 1 < NT) stage(t + 1, cur^1);

    f32x4 s[4];
    #pragma unroll
    for (int nc = 0; nc < 4; ++nc) {
      s[nc] = (f32x4){0.f,0.f,0.f,0.f};
      int R = nc*16 + c;
      #pragma unroll
      for (int kd = 0; kd < 4; ++kd) {
        bf16x8 kf = *(const bf16x8*)&Ks[cur][R*128 + (((kd*4 + g) ^ (R & 15)) * 8)];
        s[nc] = MFMA16(qf[kd], kf, s[nc]);
      }
    }

    float tm[4], rsum[4], alpha[4];
    #pragma unroll
    for (int r = 0; r < 4; ++r)
      tm[r] = fmaxf(fmaxf(s[0][r], s[1][r]), fmaxf(s[2][r], s[3][r]));
    #pragma unroll
    for (int r = 0; r < 4; ++r) {
      #pragma unroll
      for (int mask = 1; mask <= 8; mask <<= 1)
        tm[r] = fmaxf(tm[r], __shfl_xor(tm[r], mask));
      float mnew = fmaxf(mrun[r], tm[r]);
      alpha[r] = expf(mrun[r] - mnew);
      mrun[r] = mnew;
      rsum[r] = 0.f;
    }
    #pragma unroll
    for (int nc = 0; nc < 4; ++nc)
      #pragma unroll
      for (int r = 0; r < 4; ++r) {
        float p = expf(s[nc][r] - mrun[r]);
        s[nc][r] = p;
        rsum[r] += p;
      }
    #pragma unroll
    for (int r = 0; r < 4; ++r) {
      #pragma unroll
      for (int mask = 1; mask <= 8; mask <<= 1)
        rsum[r] += __shfl_xor(rsum[r], mask);
      lrun[r] = lrun[r]*alpha[r] + rsum[r];
    }
    #pragma unroll
    for (int nc = 0; nc < 8; ++nc)
      #pragma unroll
      for (int r = 0; r < 4; ++r) O[nc][r] *= alpha[r];

    #pragma unroll
    for (int nc = 0; nc < 4; ++nc)
      #pragma unroll
      for (int r = 0; r < 4; ++r)
        Pw[(g*4+r)*PPITCH + nc*16 + c] = f2bf(s[nc][r]);
    asm volatile("s_waitcnt lgkmcnt(0)" ::: "memory");
    bf16x8 pa0 = *(const bf16x8*)&Pw[c*PPITCH + g*8];
    bf16x8 pa1 = *(const bf16x8*)&Pw[c*PPITCH + 32 + g*8];

    #pragma unroll
    for (int ks = 0; ks < 2; ++ks) {
      #pragma unroll
      for (int nc = 0; nc < 8; ++nc) {
        int R = nc*16 + c;
        bf16x8 vf = *(const bf16x8*)&Vts[cur][R*64 + (((ks*4 + g) ^ (R & 7)) * 8)];
        O[nc] = MFMA16(ks ? pa1 : pa0, vf, O[nc]);
      }
    }

    if (t + 1 < NT) {
      sync_prefetch();
      cur ^= 1;
    }
  }

  short* ob = obf + ((size_t)(b*L_ + q0))*D_ + hh*HD_;
  #pragma unroll
  for (int r = 0; r < 4; ++r) {
    float inv = 1.f / lrun[r];
    #pragma unroll
    for (int nc = 0; nc < 8; ++nc)
      ob[(size_t)(g*4+r)*D_ + nc*16 + c] = f2bf(O[nc][r] * inv);
  }
}

// ---------------- heads ----------------
// lm partials: part[ks][j][VOCAB], ks=0..7 k-chunks (128 each), j=batch
__global__ __launch_bounds__(256) void lm_head_part_k(const float* __restrict__ h,
    const float* __restrict__ lm_w, float* __restrict__ part) {
  int tid = threadIdx.x;
  int n = (blockIdx.x*256 + tid)*4;
  int ks = blockIdx.y;
  __shared__ float last0[128], last1[128];
  const float* h0 = h + ((size_t)0*L_ + (L_-1))*D_ + ks*128;
  const float* h1 = h + ((size_t)1*L_ + (L_-1))*D_ + ks*128;
  if (tid < 128) { last0[tid] = h0[tid]; last1[tid] = h1[tid]; }
  __syncthreads();
  float4 a0 = {0.f,0.f,0.f,0.f}, a1 = {0.f,0.f,0.f,0.f};
  const float* wp = lm_w + (size_t)(ks*128)*VOCAB_ + n;
  for (int kk = 0; kk < 128; ++kk) {
    float4 wv = *(const float4*)(wp + (size_t)kk*VOCAB_);
    float c0 = last0[kk], c1 = last1[kk];
    a0.x += c0*wv.x; a0.y += c0*wv.y; a0.z += c0*wv.z; a0.w += c0*wv.w;
    a1.x += c1*wv.x; a1.y += c1*wv.y; a1.z += c1*wv.z; a1.w += c1*wv.w;
  }
  *(float4*)(part + ((size_t)ks*2 + 0)*VOCAB_ + n) = a0;
  *(float4*)(part + ((size_t)ks*2 + 1)*VOCAB_ + n) = a1;
}

__global__ __launch_bounds__(256) void lm_head_red_k(const float* __restrict__ part,
    float* __restrict__ out) {
  int i = blockIdx.x*256 + threadIdx.x;        // over 2*VOCAB/4 float4s
  int j = (i*4) / VOCAB_;
  int n = (i*4) & (VOCAB_-1);
  float4 acc = {0.f,0.f,0.f,0.f};
  #pragma unroll
  for (int ks = 0; ks < 8; ++ks) {
    float4 v = *(const float4*)(part + ((size_t)ks*2 + j)*VOCAB_ + n);
    acc.x += v.x; acc.y += v.y; acc.z += v.z; acc.w += v.w;
  }
  *(float4*)(out + (size_t)j*VOCAB_ + n) = acc;
}

__global__ __launch_bounds__(128) void tool_head_k(const float* __restrict__ h,
    const float* __restrict__ tw, const float* __restrict__ tb, float* __restrict__ out) {
  int b = blockIdx.x;
  int tid = threadIdx.x;
  __shared__ float last[D_];
  const float* hr = h + ((size_t)b*L_ + (L_-1))*D_;
  for (int d = tid; d < D_; d += 128) last[d] = hr[d];
  __syncthreads();
  float acc = tb[tid];
  for (int k = 0; k < D_; ++k) acc += last[k]*tw[(size_t)k*TOOLV_ + tid];
  out[(size_t)2*VOCAB_ + (size_t)b*TOOLV_ + tid] = acc;
}

extern "C" void kernel_launch(void* const* d_in, const int* in_sizes, int n_in,
                              void* d_out, int out_size, void* d_ws, size_t ws_size,
                              hipStream_t stream) {
  const float* cs        = (const float*)d_in[1];
  const float* proj_w    = (const float*)d_in[2];
  const float* emb_scale = (const float*)d_in[3];
  const float* conv_dw_w = (const float*)d_in[4];
  const float* conv_dw_b = (const float*)d_in[5];
  const float* conv_pw_w = (const float*)d_in[6];
  const float* conv_pw_b = (const float*)d_in[7];
  const float* conv_ln_s = (const float*)d_in[8];
  const float* conv_ln_b = (const float*)d_in[9];
  const float* attn_q_w  = (const float*)d_in[10];
  const float* attn_kv_w = (const float*)d_in[11];
  const float* attn_out_w= (const float*)d_in[12];
  const float* attn_ln_s = (const float*)d_in[13];
  const float* attn_ln_b = (const float*)d_in[14];
  const float* lm_w      = (const float*)d_in[15];
  const float* tool_w    = (const float*)d_in[16];
  const float* tool_b    = (const float*)d_in[17];

  const int M = B_*L_;                              // 4096
  float* hA   = (float*)d_ws;                       // M*D fp32
  float* hB   = hA   + (size_t)M*D_;                // M*D fp32 (ping-pong)
  float* buf2 = hB   + (size_t)M*D_;                // M*2D fp32 (lower: glu/proj; upper: qbf)
  short* kbf  = (short*)(buf2 + (size_t)M*2*D_);    // B*H*L*128 bf16
  short* vtbf = kbf + (size_t)B_*HEADS_*L_*128;     // B*H*128*L bf16
  short* abf  = (short*)(vtbf + (size_t)B_*HEADS_*128*L_);  // M*D bf16
  short* wconv= abf + (size_t)M*D_;                 // 10 * 2D*D bf16 (permuted)
  short* wqkv = wconv + (size_t)NCONV_*2*D_*D_;     // 6 * 3D*D bf16
  short* wout = wqkv + (size_t)NATTN_*3*D_*D_;      // 6 * D*D bf16
  float* lmpart = (float*)(wout + (size_t)NATTN_*D_*D_);  // 8*2*VOCAB fp32
  short* qbf  = (short*)(buf2 + (size_t)M*D_);      // M*D bf16 (upper half of buf2)

  const float scale = 0.088388347648318447f;        // 128^-0.5

  // ---- batched weight prep (3 launches) ----
  {
    cvt_perm_k<<<dim3((2*D_*D_/4)/256, NCONV_), 256, 0, stream>>>(conv_pw_w, wconv);
    transp_qo_k<<<dim3(D_/32, D_/32, 2*NATTN_), 256, 0, stream>>>(
        attn_q_w, attn_out_w, wqkv, wout);
    transp_bf16_k<<<dim3((2*D_)/32, D_/32, NATTN_), 256, 0, stream>>>(
        attn_kv_w, wqkv + (size_t)D_*D_, D_, 2*D_, (size_t)D_*2*D_, (size_t)3*D_*D_);
  }

  julia_proj_k<<<M, 256, 0, stream>>>(cs, proj_w, emb_scale, hA);

  // layer-0 depthwise conv (standalone; subsequent ones are fused into LN)
  dwconv_k<<<(M*D_/4)/256, 256, 0, stream>>>(hA, conv_dw_w, conv_dw_b, abf);

  float* hc = hA;
  float* hn = hB;
  for (int i = 0; i < NCONV_ - 1; ++i) {
    gemm_bf16<4, 128><<<dim3(M/128, (2*D_)/128), 256, 0, stream>>>(
        abf, wconv + (size_t)i*2*D_*D_, conv_pw_b + (size_t)i*2*D_,
        buf2, nullptr, nullptr, nullptr, 1.f, M, 2*D_, D_);
    ln_dwconv_k<<<M/8, 256, 0, stream>>>(hc, buf2,
        conv_ln_s + (size_t)i*D_, conv_ln_b + (size_t)i*D_,
        conv_dw_w + (size_t)(i+1)*D_*5, conv_dw_b + (size_t)(i+1)*D_,
        hn, abf);
    float* tmp = hc; hc = hn; hn = tmp;
  }
  // layer 9: GEMM + plain LN (emits bf16 h for the attention section)
  gemm_bf16<4, 128><<<dim3(M/128, (2*D_)/128), 256, 0, stream>>>(
      abf, wconv + (size_t)(NCONV_-1)*2*D_*D_, conv_pw_b + (size_t)(NCONV_-1)*2*D_,
      buf2, nullptr, nullptr, nullptr, 1.f, M, 2*D_, D_);
  resid_ln_k<<<M, 256, 0, stream>>>(hc, buf2,
      conv_ln_s + (size_t)(NCONV_-1)*D_, conv_ln_b + (size_t)(NCONV_-1)*D_, abf);

  for (int i = 0; i < NATTN_; ++i) {
    // abf holds bf16(h) from previous LN
    gemm_bf16<3, 128><<<dim3(M/128, (3*D_)/128), 256, 0, stream>>>(
        abf, wqkv + (size_t)i*3*D_*D_, nullptr, nullptr, qbf, kbf, vtbf,
        scale, M, 3*D_, D_);
    attn2_k<<<(L_/64)*HEADS_*B_, 256, 0, stream>>>(qbf, kbf, vtbf, abf);
    gemm_bf16<0, 64><<<dim3(M/128, D_/64), 256, 0, stream>>>(
        abf, wout + (size_t)i*D_*D_, nullptr, buf2, nullptr, nullptr, nullptr,
        1.f, M, D_, D_);
    resid_ln_k<<<M, 256, 0, stream>>>(hc, buf2, attn_ln_s + (size_t)i*D_,
                                      attn_ln_b + (size_t)i*D_,
                                      (i < NATTN_-1) ? abf : (short*)nullptr);
  }

  lm_head_part_k<<<dim3(VOCAB_/1024, 8), 256, 0, stream>>>(hc, lm_w, lmpart);
  lm_head_red_k<<<(2*VOCAB_/4)/256, 256, 0, stream>>>(lmpart, (float*)d_out);
  tool_head_k<<<B_, 128, 0, stream>>>(hc, tool_w, tool_b, (float*)d_out);
}